// Round 6
// baseline (4039.626 us; speedup 1.0000x reference)
//
#include <hip/hip_runtime.h>
#include <hip/hip_bf16.h>

#define DIM 512
#define BATCH 32
#define PLANE (BATCH * DIM * DIM)

// ---------------------------------------------------------------------------
// Kernel 1: build A = M/64 densely. M = alpha*a_dag - conj(alpha)*a.
//   M[i][i-1] = alpha*sqrt(i)          (subdiagonal)
//   M[i][i+1] = -conj(alpha)*sqrt(i+1) (superdiagonal)
// ---------------------------------------------------------------------------
__global__ __launch_bounds__(256) void build_A(const float* __restrict__ bxp,
                                               const float* __restrict__ bpp,
                                               float2* __restrict__ A) {
    const int idx = blockIdx.x * blockDim.x + threadIdx.x;
    const int i = idx >> 9, j = idx & (DIM - 1);
    const float bx = bxp[0], bp = bpp[0];
    const float inv = 1.f / 64.f;  // s = 6 scalings
    float re = 0.f, im = 0.f;
    if (j == i - 1) { float g = sqrtf((float)i)       * inv; re =  bx * g; im = bp * g; }
    if (j == i + 1) { float g = sqrtf((float)(i + 1)) * inv; re = -bx * g; im = bp * g; }
    A[idx] = make_float2(re, im);
}

// ---------------------------------------------------------------------------
// Kernel 2: T = I + c0 * A
// ---------------------------------------------------------------------------
__global__ __launch_bounds__(256) void init_T(const float2* __restrict__ A,
                                              float2* __restrict__ T, float c0) {
    const int idx = blockIdx.x * blockDim.x + threadIdx.x;
    const int i = idx >> 9, j = idx & (DIM - 1);
    const float2 a = A[idx];
    T[idx] = make_float2(a.x * c0 + (i == j ? 1.f : 0.f), a.y * c0);
}

// ---------------------------------------------------------------------------
// Kernel 3: dense complex GEMM: C = scale*(A @ B) + addI*I.   (cross-validated:
// r1 banded-Taylor path and r2 Horner path agree bit-identically)
// ---------------------------------------------------------------------------
__global__ __launch_bounds__(256) void zgemm(const float2* __restrict__ A,
                                             const float2* __restrict__ B,
                                             float2* __restrict__ C,
                                             float scale, int addI) {
    __shared__ float2 As[16][64];  // As[l][i] = A[i0+i][lt+l]
    __shared__ float2 Bs[16][64];  // Bs[l][j] = B[lt+l][j0+j]
    const int j0 = blockIdx.x * 64, i0 = blockIdx.y * 64;
    const int tid = threadIdx.x;
    const int tx = tid & 15, ty = tid >> 4;
    float cre[4][4] = {{0.f}}, cim[4][4] = {{0.f}};
    for (int lt = 0; lt < DIM; lt += 16) {
        for (int idx = tid; idx < 1024; idx += 256) {
            const int r = idx >> 4, c = idx & 15;
            As[c][r] = A[(i0 + r) * DIM + lt + c];
            const int rr = idx >> 6, cc = idx & 63;
            Bs[rr][cc] = B[(lt + rr) * DIM + j0 + cc];
        }
        __syncthreads();
#pragma unroll
        for (int l = 0; l < 16; ++l) {
            float are[4], aim[4], bre[4], bim[4];
#pragma unroll
            for (int q = 0; q < 4; ++q) { float2 v = As[l][ty * 4 + q]; are[q] = v.x; aim[q] = v.y; }
#pragma unroll
            for (int r = 0; r < 4; ++r) { float2 v = Bs[l][tx * 4 + r]; bre[r] = v.x; bim[r] = v.y; }
#pragma unroll
            for (int q = 0; q < 4; ++q)
#pragma unroll
                for (int r = 0; r < 4; ++r) {
                    cre[q][r] += are[q] * bre[r] - aim[q] * bim[r];
                    cim[q][r] += are[q] * bim[r] + aim[q] * bre[r];
                }
        }
        __syncthreads();
    }
#pragma unroll
    for (int q = 0; q < 4; ++q)
#pragma unroll
        for (int r = 0; r < 4; ++r) {
            const int gi = i0 + ty * 4 + q, gj = j0 + tx * 4 + r;
            float re = cre[q][r] * scale, im = cim[q][r] * scale;
            if (addI && gi == gj) re += 1.f;
            C[gi * DIM + gj] = make_float2(re, im);
        }
}

// ---------------------------------------------------------------------------
// Kernel 4: batched apply, FLOAT32 output.
//   y[b,m,k] = e^{+i*kappa*m^2} * sum_j D[m,j] * e^{-i*(th1+th2)*j} * x[b,j,k]
// out_size == PLANE   : write real(y) as float32, [b][m][k]   (expected case)
// out_size >= 2*PLANE : write (re,im) interleaved float32 (fallback)
// ---------------------------------------------------------------------------
__global__ __launch_bounds__(256) void apply_dumb(const float2* __restrict__ D,
                                                  const float* __restrict__ xre,
                                                  const float* __restrict__ xim,
                                                  const float* __restrict__ th1p,
                                                  const float* __restrict__ th2p,
                                                  const float* __restrict__ kapp,
                                                  float* __restrict__ out,
                                                  int interleaved) {
    __shared__ float2 As[16][64];  // As[l][m'] = D[m0+m'][lt+l]
    __shared__ float2 Bs[16][64];  // Bs[l][k'] = e^{-i*theta*(lt+l)} x[b][lt+l][k0+k']
    const int k0 = blockIdx.x * 64, m0 = blockIdx.y * 64, bz = blockIdx.z;
    const int tid = threadIdx.x;
    const int tx = tid & 15, ty = tid >> 4;
    const float theta = th1p[0] + th2p[0];
    const float kap = kapp[0];
    const size_t xbase = (size_t)bz * DIM * DIM;

    float cre[4][4] = {{0.f}}, cim[4][4] = {{0.f}};
    for (int lt = 0; lt < DIM; lt += 16) {
        for (int idx = tid; idx < 1024; idx += 256) {
            const int r = idx >> 4, c = idx & 15;
            As[c][r] = D[(m0 + r) * DIM + lt + c];
            const int rr = idx >> 6, cc = idx & 63;
            const int j = lt + rr;
            const size_t xo = xbase + (size_t)j * DIM + k0 + cc;
            const float xr = xre[xo], xi = xim[xo];
            float s, cph;
            sincosf(-theta * (float)j, &s, &cph);
            Bs[rr][cc] = make_float2(xr * cph - xi * s, xr * s + xi * cph);
        }
        __syncthreads();
#pragma unroll
        for (int l = 0; l < 16; ++l) {
            float are[4], aim[4], bre[4], bim[4];
#pragma unroll
            for (int q = 0; q < 4; ++q) { float2 v = As[l][ty * 4 + q]; are[q] = v.x; aim[q] = v.y; }
#pragma unroll
            for (int r = 0; r < 4; ++r) { float2 v = Bs[l][tx * 4 + r]; bre[r] = v.x; bim[r] = v.y; }
#pragma unroll
            for (int q = 0; q < 4; ++q)
#pragma unroll
                for (int r = 0; r < 4; ++r) {
                    cre[q][r] += are[q] * bre[r] - aim[q] * bim[r];
                    cim[q][r] += are[q] * bim[r] + aim[q] * bre[r];
                }
        }
        __syncthreads();
    }

#pragma unroll
    for (int q = 0; q < 4; ++q) {
        const int m = m0 + ty * 4 + q;
        float sm, cm;
        sincosf(kap * (float)(m * m), &sm, &cm);  // e^{+i*kappa*m^2}
        const size_t off = (size_t)((size_t)bz * DIM + m) * DIM + (k0 + tx * 4);
        if (interleaved) {
#pragma unroll
            for (int r = 0; r < 4; ++r) {
                const float yre = cre[q][r] * cm - cim[q][r] * sm;
                const float yim = cre[q][r] * sm + cim[q][r] * cm;
                *reinterpret_cast<float2*>(out + 2 * (off + r)) = make_float2(yre, yim);
            }
        } else {
            float4 v;
            v.x = cre[q][0] * cm - cim[q][0] * sm;
            v.y = cre[q][1] * cm - cim[q][1] * sm;
            v.z = cre[q][2] * cm - cim[q][2] * sm;
            v.w = cre[q][3] * cm - cim[q][3] * sm;
            *reinterpret_cast<float4*>(out + off) = v;
        }
    }
}

// ---------------------------------------------------------------------------
extern "C" void kernel_launch(void* const* d_in, const int* in_sizes, int n_in,
                              void* d_out, int out_size, void* d_ws, size_t ws_size,
                              hipStream_t stream) {
    const float* xre = (const float*)d_in[0];
    const float* xim = (const float*)d_in[1];
    const float* th1 = (const float*)d_in[2];
    const float* th2 = (const float*)d_in[3];
    // d_in[4] = r : squeezing generator is exactly zero -> S = I, unused.
    const float* bx  = (const float*)d_in[5];
    const float* bp  = (const float*)d_in[6];
    const float* kap = (const float*)d_in[7];
    float* out = (float*)d_out;

    float2* A   = (float2*)d_ws;           // 2 MB each
    float2* T0  = A  + DIM * DIM;
    float2* T1  = T0 + DIM * DIM;

    const dim3 eb(256), eg(DIM * DIM / 256);

    // A = M/64
    hipLaunchKernelGGL(build_A, eg, eb, 0, stream, bx, bp, A);
    // Horner: T = I + A/12
    hipLaunchKernelGGL(init_T, eg, eb, 0, stream, A, T0, 1.f / 12.f);
    float2* cur = T0; float2* nxt = T1;
    for (int k = 11; k >= 1; --k) {
        hipLaunchKernelGGL(zgemm, dim3(8, 8), dim3(256), 0, stream,
                           A, cur, nxt, 1.f / (float)k, 1);
        float2* t = cur; cur = nxt; nxt = t;
    }
    // 6 squarings: expm(M/64)^64 = expm(M)
    for (int s = 0; s < 6; ++s) {
        hipLaunchKernelGGL(zgemm, dim3(8, 8), dim3(256), 0, stream,
                           cur, cur, nxt, 1.f, 0);
        float2* t = cur; cur = nxt; nxt = t;
    }

    // y[b] = K * (D @ (Theta * x[b])) — float32 output.
    const int interleaved = (out_size >= 2 * PLANE) ? 1 : 0;
    hipLaunchKernelGGL(apply_dumb, dim3(8, 8, BATCH), dim3(256), 0, stream,
                       cur, xre, xim, th1, th2, kap, out, interleaved);
}

// Round 7
// 473.644 us; speedup vs baseline: 8.5288x; 8.5288x over previous
//
#include <hip/hip_runtime.h>
#include <hip/hip_bf16.h>

#define DIM 512
#define BATCH 32
#define PLANE (BATCH * DIM * DIM)

// ---------------------------------------------------------------------------
// Kernel 1: Taylor series of expm(A), A = M/8 tridiagonal, per-row via waves.
// (bit-validated in r1/r2: agrees with dense Horner s=6 chain exactly)
// ---------------------------------------------------------------------------
__global__ __launch_bounds__(256) void taylor_rows(const float* __restrict__ bxp,
                                                   const float* __restrict__ bpp,
                                                   float2* __restrict__ E) {
    const int wave = (blockIdx.x * blockDim.x + threadIdx.x) >> 6;
    const int lane = threadIdx.x & 63;
    if (wave >= DIM) return;
    const int i = wave;
    const float bx = bxp[0], bp = bpp[0];
    const float inv2s = 0.125f;  // s = 3 scalings
    const int o = lane - 31;
    const int j = i + o;
    const bool jvalid = (j >= 0 && j < DIM);

    float pre = 0.f, pim = 0.f;
    if (o == -1 && i >= 1)      { float g = sqrtf((float)i)       * inv2s; pre =  bx * g; pim = bp * g; }
    if (o ==  1 && i + 1 < DIM) { float g = sqrtf((float)(i + 1)) * inv2s; pre = -bx * g; pim = bp * g; }
    float ere = (o == 0 ? 1.f : 0.f) + pre;
    float eim = pim;

    const float gs = (jvalid && j >= 1)       ? sqrtf((float)j)       * inv2s : 0.f;
    const float hs = (jvalid && j + 1 < DIM)  ? sqrtf((float)(j + 1)) * inv2s : 0.f;
    const float csup_re = -bx * gs, csup_im = bp * gs;
    const float csub_re =  bx * hs, csub_im = bp * hs;

    for (int k = 2; k <= 24; ++k) {
        const float invk = 1.f / (float)k;
        float pmre = __shfl_up(pre, 1, 64),   pmim = __shfl_up(pim, 1, 64);
        float ppre = __shfl_down(pre, 1, 64), ppim = __shfl_down(pim, 1, 64);
        if (lane == 0)  { pmre = 0.f; pmim = 0.f; }
        if (lane == 63) { ppre = 0.f; ppim = 0.f; }
        float nre = pmre * csup_re - pmim * csup_im + ppre * csub_re - ppim * csub_im;
        float nim = pmre * csup_im + pmim * csup_re + ppre * csub_im + ppim * csub_re;
        pre = nre * invk; pim = nim * invk;
        ere += pre; eim += pim;
    }

    for (int base = 0; base < DIM; base += 64) {
        const int c = base + lane;
        const int src = c - i + 31;
        const float tre = __shfl(ere, src & 63, 64);
        const float tim = __shfl(eim, src & 63, 64);
        float vre = 0.f, vim = 0.f;
        if (src >= 0 && src < 64) { vre = tre; vim = tim; }
        E[i * DIM + c] = make_float2(vre, vim);
    }
}

// ---------------------------------------------------------------------------
// Kernel 2: band-aware complex square C = A*A (validated in r1).
// ---------------------------------------------------------------------------
__global__ __launch_bounds__(256) void csq(const float2* __restrict__ A,
                                           float2* __restrict__ C, int bIn) {
    __shared__ float2 At[16][64];
    __shared__ float2 Bt[16][64];
    const int j0 = blockIdx.x * 64, i0 = blockIdx.y * 64;
    const int tid = threadIdx.x;
    const int tx = tid & 15, ty = tid >> 4;
    const int lmin = max(0, max(i0, j0) - bIn);
    const int lmax = min(DIM, min(i0, j0) + 64 + bIn);

    float cre[4][4] = {{0.f}}, cim[4][4] = {{0.f}};
    for (int lt = lmin; lt < lmax; lt += 16) {
        for (int idx = tid; idx < 1024; idx += 256) {
            const int r = idx >> 4, c = idx & 15;
            const int l = lt + c;
            At[c][r] = (l < lmax) ? A[(i0 + r) * DIM + l] : make_float2(0.f, 0.f);
            const int rr = idx >> 6, cc = idx & 63;
            const int l2 = lt + rr;
            Bt[rr][cc] = (l2 < lmax) ? A[l2 * DIM + j0 + cc] : make_float2(0.f, 0.f);
        }
        __syncthreads();
        float are[4], aim[4], bre[4], bim[4];
#pragma unroll
        for (int ll = 0; ll < 16; ++ll) {
#pragma unroll
            for (int q = 0; q < 4; ++q) { float2 v = At[ll][ty * 4 + q]; are[q] = v.x; aim[q] = v.y; }
#pragma unroll
            for (int r = 0; r < 4; ++r) { float2 v = Bt[ll][tx * 4 + r]; bre[r] = v.x; bim[r] = v.y; }
#pragma unroll
            for (int q = 0; q < 4; ++q)
#pragma unroll
                for (int r = 0; r < 4; ++r) {
                    cre[q][r] += are[q] * bre[r] - aim[q] * bim[r];
                    cim[q][r] += are[q] * bim[r] + aim[q] * bre[r];
                }
        }
        __syncthreads();
    }
#pragma unroll
    for (int q = 0; q < 4; ++q)
#pragma unroll
        for (int r = 0; r < 4; ++r)
            C[(i0 + ty * 4 + q) * DIM + (j0 + tx * 4 + r)] = make_float2(cre[q][r], cim[q][r]);
}

// ---------------------------------------------------------------------------
// Kernel 3: fold phases into D and build the transposed real-GEMM operand:
//   D' = e^{+i*kappa*m^2} * D[m][j] * e^{-i*theta*j}
//   Gt[j*512+m] = (D'_re, -D'_im)
// ---------------------------------------------------------------------------
__global__ __launch_bounds__(256) void fold_gt(const float2* __restrict__ D,
                                               float2* __restrict__ Gt,
                                               const float* __restrict__ th1p,
                                               const float* __restrict__ th2p,
                                               const float* __restrict__ kapp) {
    const int idx = blockIdx.x * blockDim.x + threadIdx.x;  // = j*512 + m
    const int m = idx & (DIM - 1), j = idx >> 9;
    const float theta = th1p[0] + th2p[0];
    const float kap = kapp[0];
    const float2 d = D[m * DIM + j];
    float sj, cj, sm, cm;
    sincosf(-theta * (float)j, &sj, &cj);
    sincosf(kap * (float)(m * m), &sm, &cm);
    const float r1 = d.x * cj - d.y * sj;
    const float i1 = d.x * sj + d.y * cj;
    const float r2 = r1 * cm - i1 * sm;
    const float i2 = r1 * sm + i1 * cm;
    Gt[idx] = make_float2(r2, -i2);
}

// ---------------------------------------------------------------------------
// Kernel 4: banded real-output batched GEMM.
//   y_re[b,m,k] = sum_j Gt[j][m].x * xre[b,j,k] + Gt[j][m].y * xim[b,j,k]
// 128x128 tile, 256 threads, 8x8 per thread, strided per-thread mapping
// (m' = ty+16q, k' = tx+16r) -> conflict-free LDS reads. Band |m-j| <= 64.
// ---------------------------------------------------------------------------
#define BM 128
#define BK 128
__global__ __launch_bounds__(256) void apply_real(const float2* __restrict__ Gt,
                                                  const float* __restrict__ xre,
                                                  const float* __restrict__ xim,
                                                  float* __restrict__ out) {
    __shared__ float2 As[16][BM];   // As[l][m'] = Gt[(jt+l)*512 + m0+m']
    __shared__ float2 Bs[16][BK];   // Bs[l][k'] = (xre, xim)[b][jt+l][k0+k']
    const int k0 = blockIdx.x * BK, m0 = blockIdx.y * BM, bz = blockIdx.z;
    const int tid = threadIdx.x;
    const int tx = tid & 15, ty = tid >> 4;
    const int jmin = max(0, m0 - 64);
    const int jmax = min(DIM, m0 + BM + 64);   // multiples of 16, no tail
    const size_t xbase = (size_t)bz * DIM * DIM;

    float acc[8][8] = {{0.f}};
    for (int jt = jmin; jt < jmax; jt += 16) {
        for (int idx = tid; idx < 16 * BM; idx += 256) {
            const int l = idx >> 7, c = idx & (BM - 1);
            As[l][c] = Gt[(size_t)(jt + l) * DIM + m0 + c];
            const size_t xo = xbase + (size_t)(jt + l) * DIM + k0 + c;
            Bs[l][c] = make_float2(xre[xo], xim[xo]);
        }
        __syncthreads();
#pragma unroll
        for (int l = 0; l < 16; ++l) {
            float ar[8], ai[8], br[8], bi[8];
#pragma unroll
            for (int q = 0; q < 8; ++q) { float2 v = As[l][ty + 16 * q]; ar[q] = v.x; ai[q] = v.y; }
#pragma unroll
            for (int r = 0; r < 8; ++r) { float2 v = Bs[l][tx + 16 * r]; br[r] = v.x; bi[r] = v.y; }
#pragma unroll
            for (int q = 0; q < 8; ++q)
#pragma unroll
                for (int r = 0; r < 8; ++r)
                    acc[q][r] += ar[q] * br[r] + ai[q] * bi[r];
        }
        __syncthreads();
    }

#pragma unroll
    for (int q = 0; q < 8; ++q) {
        const int m = m0 + ty + 16 * q;
        const size_t off = (size_t)((size_t)bz * DIM + m) * DIM + k0 + tx;
#pragma unroll
        for (int r = 0; r < 8; ++r)
            out[off + 16 * r] = acc[q][r];
    }
}

// ---------------------------------------------------------------------------
extern "C" void kernel_launch(void* const* d_in, const int* in_sizes, int n_in,
                              void* d_out, int out_size, void* d_ws, size_t ws_size,
                              hipStream_t stream) {
    const float* xre = (const float*)d_in[0];
    const float* xim = (const float*)d_in[1];
    const float* th1 = (const float*)d_in[2];
    const float* th2 = (const float*)d_in[3];
    // d_in[4] = r : squeezing generator is exactly zero -> S = I, unused.
    const float* bx  = (const float*)d_in[5];
    const float* bp  = (const float*)d_in[6];
    const float* kap = (const float*)d_in[7];
    float* out = (float*)d_out;

    float2* bufA = (float2*)d_ws;          // 2 MB each
    float2* bufB = bufA + DIM * DIM;
    float2* bufC = bufB + DIM * DIM;

    // E = expm(M/8) (Taylor, band 24) — r1-validated path
    hipLaunchKernelGGL(taylor_rows, dim3(128), dim3(256), 0, stream, bx, bp, bufA);
    // three squarings: expm(M/8)^8 = expm(M)
    hipLaunchKernelGGL(csq, dim3(8, 8), dim3(256), 0, stream, bufA, bufB, 24);
    hipLaunchKernelGGL(csq, dim3(8, 8), dim3(256), 0, stream, bufB, bufA, 48);
    hipLaunchKernelGGL(csq, dim3(8, 8), dim3(256), 0, stream, bufA, bufB, 96);
    // fold Kerr + rotation phases, build transposed (re, -im) operand
    hipLaunchKernelGGL(fold_gt, dim3(DIM * DIM / 256), dim3(256), 0, stream,
                       bufB, bufC, th1, th2, kap);
    // y_re[b] = real(K * D'' @ x[b]) — banded real GEMM, fp32 output
    hipLaunchKernelGGL(apply_real, dim3(DIM / BK, DIM / BM, BATCH), dim3(256), 0, stream,
                       bufC, xre, xim, out);
}

// Round 8
// 173.036 us; speedup vs baseline: 23.3456x; 2.7373x over previous
//
#include <hip/hip_runtime.h>
#include <hip/hip_bf16.h>
#include <hip/hip_fp16.h>

#define DIM 512
#define BATCH 32
#define PLANE (BATCH * DIM * DIM)

typedef _Float16 half8 __attribute__((ext_vector_type(8)));
typedef float floatx4 __attribute__((ext_vector_type(4)));

static __device__ __forceinline__ unsigned short f2h(float f) {
    __half h = __float2half(f);
    return *reinterpret_cast<unsigned short*>(&h);
}

// ---------------------------------------------------------------------------
// Kernel 1: Taylor of expm(M/8), tridiagonal, one wave per row (r1-validated).
// ---------------------------------------------------------------------------
__global__ __launch_bounds__(256) void taylor_rows(const float* __restrict__ bxp,
                                                   const float* __restrict__ bpp,
                                                   float2* __restrict__ E) {
    const int wave = (blockIdx.x * blockDim.x + threadIdx.x) >> 6;
    const int lane = threadIdx.x & 63;
    if (wave >= DIM) return;
    const int i = wave;
    const float bx = bxp[0], bp = bpp[0];
    const float inv2s = 0.125f;
    const int o = lane - 31;
    const int j = i + o;
    const bool jvalid = (j >= 0 && j < DIM);

    float pre = 0.f, pim = 0.f;
    if (o == -1 && i >= 1)      { float g = sqrtf((float)i)       * inv2s; pre =  bx * g; pim = bp * g; }
    if (o ==  1 && i + 1 < DIM) { float g = sqrtf((float)(i + 1)) * inv2s; pre = -bx * g; pim = bp * g; }
    float ere = (o == 0 ? 1.f : 0.f) + pre;
    float eim = pim;

    const float gs = (jvalid && j >= 1)       ? sqrtf((float)j)       * inv2s : 0.f;
    const float hs = (jvalid && j + 1 < DIM)  ? sqrtf((float)(j + 1)) * inv2s : 0.f;
    const float csup_re = -bx * gs, csup_im = bp * gs;
    const float csub_re =  bx * hs, csub_im = bp * hs;

    for (int k = 2; k <= 24; ++k) {
        const float invk = 1.f / (float)k;
        float pmre = __shfl_up(pre, 1, 64),   pmim = __shfl_up(pim, 1, 64);
        float ppre = __shfl_down(pre, 1, 64), ppim = __shfl_down(pim, 1, 64);
        if (lane == 0)  { pmre = 0.f; pmim = 0.f; }
        if (lane == 63) { ppre = 0.f; ppim = 0.f; }
        float nre = pmre * csup_re - pmim * csup_im + ppre * csub_re - ppim * csub_im;
        float nim = pmre * csup_im + pmim * csup_re + ppre * csub_im + ppim * csub_re;
        pre = nre * invk; pim = nim * invk;
        ere += pre; eim += pim;
    }

    for (int base = 0; base < DIM; base += 64) {
        const int c = base + lane;
        const int src = c - i + 31;
        const float tre = __shfl(ere, src & 63, 64);
        const float tim = __shfl(eim, src & 63, 64);
        float vre = 0.f, vim = 0.f;
        if (src >= 0 && src < 64) { vre = tre; vim = tim; }
        E[i * DIM + c] = make_float2(vre, vim);
    }
}

// ---------------------------------------------------------------------------
// Kernel 2: band-aware complex square C = A*A (r1-validated).
// ---------------------------------------------------------------------------
__global__ __launch_bounds__(256) void csq(const float2* __restrict__ A,
                                           float2* __restrict__ C, int bIn) {
    __shared__ float2 At[16][64];
    __shared__ float2 Bt[16][64];
    const int j0 = blockIdx.x * 64, i0 = blockIdx.y * 64;
    const int tid = threadIdx.x;
    const int tx = tid & 15, ty = tid >> 4;
    const int lmin = max(0, max(i0, j0) - bIn);
    const int lmax = min(DIM, min(i0, j0) + 64 + bIn);

    float cre[4][4] = {{0.f}}, cim[4][4] = {{0.f}};
    for (int lt = lmin; lt < lmax; lt += 16) {
        for (int idx = tid; idx < 1024; idx += 256) {
            const int r = idx >> 4, c = idx & 15;
            const int l = lt + c;
            At[c][r] = (l < lmax) ? A[(i0 + r) * DIM + l] : make_float2(0.f, 0.f);
            const int rr = idx >> 6, cc = idx & 63;
            const int l2 = lt + rr;
            Bt[rr][cc] = (l2 < lmax) ? A[l2 * DIM + j0 + cc] : make_float2(0.f, 0.f);
        }
        __syncthreads();
        float are[4], aim[4], bre[4], bim[4];
#pragma unroll
        for (int ll = 0; ll < 16; ++ll) {
#pragma unroll
            for (int q = 0; q < 4; ++q) { float2 v = At[ll][ty * 4 + q]; are[q] = v.x; aim[q] = v.y; }
#pragma unroll
            for (int r = 0; r < 4; ++r) { float2 v = Bt[ll][tx * 4 + r]; bre[r] = v.x; bim[r] = v.y; }
#pragma unroll
            for (int q = 0; q < 4; ++q)
#pragma unroll
                for (int r = 0; r < 4; ++r) {
                    cre[q][r] += are[q] * bre[r] - aim[q] * bim[r];
                    cim[q][r] += are[q] * bim[r] + aim[q] * bre[r];
                }
        }
        __syncthreads();
    }
#pragma unroll
    for (int q = 0; q < 4; ++q)
#pragma unroll
        for (int r = 0; r < 4; ++r)
            C[(i0 + ty * 4 + q) * DIM + (j0 + tx * 4 + r)] = make_float2(cre[q][r], cim[q][r]);
}

// ---------------------------------------------------------------------------
// Kernel 2b: last squaring FUSED with phase fold -> fp16 Gp[m][2j+c].
//   D = A*A;  D' = e^{+i*kappa*m^2} * D[m][j] * e^{-i*theta*j}
//   Gp[m][2j] = fp16(Re D'), Gp[m][2j+1] = fp16(-Im D')
// ---------------------------------------------------------------------------
__global__ __launch_bounds__(256) void csq_fold(const float2* __restrict__ A,
                                                unsigned short* __restrict__ Gp,
                                                const float* __restrict__ th1p,
                                                const float* __restrict__ th2p,
                                                const float* __restrict__ kapp,
                                                int bIn) {
    __shared__ float2 At[16][64];
    __shared__ float2 Bt[16][64];
    const int j0 = blockIdx.x * 64, i0 = blockIdx.y * 64;
    const int tid = threadIdx.x;
    const int tx = tid & 15, ty = tid >> 4;
    const int lmin = max(0, max(i0, j0) - bIn);
    const int lmax = min(DIM, min(i0, j0) + 64 + bIn);

    float cre[4][4] = {{0.f}}, cim[4][4] = {{0.f}};
    for (int lt = lmin; lt < lmax; lt += 16) {
        for (int idx = tid; idx < 1024; idx += 256) {
            const int r = idx >> 4, c = idx & 15;
            const int l = lt + c;
            At[c][r] = (l < lmax) ? A[(i0 + r) * DIM + l] : make_float2(0.f, 0.f);
            const int rr = idx >> 6, cc = idx & 63;
            const int l2 = lt + rr;
            Bt[rr][cc] = (l2 < lmax) ? A[l2 * DIM + j0 + cc] : make_float2(0.f, 0.f);
        }
        __syncthreads();
        float are[4], aim[4], bre[4], bim[4];
#pragma unroll
        for (int ll = 0; ll < 16; ++ll) {
#pragma unroll
            for (int q = 0; q < 4; ++q) { float2 v = At[ll][ty * 4 + q]; are[q] = v.x; aim[q] = v.y; }
#pragma unroll
            for (int r = 0; r < 4; ++r) { float2 v = Bt[ll][tx * 4 + r]; bre[r] = v.x; bim[r] = v.y; }
#pragma unroll
            for (int q = 0; q < 4; ++q)
#pragma unroll
                for (int r = 0; r < 4; ++r) {
                    cre[q][r] += are[q] * bre[r] - aim[q] * bim[r];
                    cim[q][r] += are[q] * bim[r] + aim[q] * bre[r];
                }
        }
        __syncthreads();
    }

    const float theta = th1p[0] + th2p[0];
    const float kap = kapp[0];
#pragma unroll
    for (int q = 0; q < 4; ++q) {
        const int m = i0 + ty * 4 + q;
        float sm, cm;
        sincosf(kap * (float)(m * m), &sm, &cm);
#pragma unroll
        for (int r = 0; r < 4; ++r) {
            const int j = j0 + tx * 4 + r;
            float sj, cj;
            sincosf(-theta * (float)j, &sj, &cj);
            const float r1 = cre[q][r] * cj - cim[q][r] * sj;
            const float i1 = cre[q][r] * sj + cim[q][r] * cj;
            const float r2 = r1 * cm - i1 * sm;
            const float i2 = r1 * sm + i1 * cm;
            *reinterpret_cast<ushort2*>(Gp + (size_t)m * 1024 + 2 * j) =
                make_ushort2(f2h(r2), f2h(-i2));
        }
    }
}

// ---------------------------------------------------------------------------
// Kernel 3: X transpose+pack: Xt[b][k][2j+c] = fp16(x{re,im}[b][j][k]).
// 64x64 tiles via LDS, coalesced both sides.
// ---------------------------------------------------------------------------
__global__ __launch_bounds__(256) void xt_build(const float* __restrict__ xre,
                                                const float* __restrict__ xim,
                                                unsigned short* __restrict__ Xt) {
    __shared__ ushort2 T[64][65];
    const int j0 = blockIdx.x * 64, k0 = blockIdx.y * 64, b = blockIdx.z;
    const int tid = threadIdx.x;

    for (int p = tid; p < 1024; p += 256) {
        const int jr = p >> 4, seg = p & 15, koff = seg * 4;
        const size_t base = ((size_t)b * DIM + j0 + jr) * DIM + k0 + koff;
        const float4 xr = *reinterpret_cast<const float4*>(xre + base);
        const float4 xi = *reinterpret_cast<const float4*>(xim + base);
        T[jr][koff + 0] = make_ushort2(f2h(xr.x), f2h(xi.x));
        T[jr][koff + 1] = make_ushort2(f2h(xr.y), f2h(xi.y));
        T[jr][koff + 2] = make_ushort2(f2h(xr.z), f2h(xi.z));
        T[jr][koff + 3] = make_ushort2(f2h(xr.w), f2h(xi.w));
    }
    __syncthreads();

    for (int p = tid; p < 1024; p += 256) {
        const int k = p >> 4, seg = p & 15;
        union { ushort2 u[4]; float4 v; } pk;
#pragma unroll
        for (int jj = 0; jj < 4; ++jj)
            pk.u[jj] = T[seg * 4 + jj][k];
        unsigned short* dst = Xt + ((size_t)b * DIM + k0 + k) * 1024 + 2 * (j0 + seg * 4);
        *reinterpret_cast<float4*>(dst) = pk.v;
    }
}

// ---------------------------------------------------------------------------
// Kernel 4: MFMA apply. out[b][m][k] = sum_Kd Gp[m][Kd] * Xt[b][k][Kd],
// Kd = 2j+c band-restricted to j in [m0-64, m0+192). fp16 in, fp32 acc/out.
// No LDS, no barriers: fragments loaded directly from global (G is L2-hot).
// Block 256 thr = 4 waves (2x2), tile 128m x 128k, wave tile 64x64.
// mfma_f32_16x16x32_f16 layouts: A row=lane&15, k=8*(lane>>4)+i;
// B col=lane&15, same k; C/D col=lane&15, row=4*(lane>>4)+reg.
// ---------------------------------------------------------------------------
__global__ __launch_bounds__(256) void apply_mfma(const unsigned short* __restrict__ Gp,
                                                  const unsigned short* __restrict__ Xt,
                                                  float* __restrict__ out) {
    const int k0 = blockIdx.x * 128, m0 = blockIdx.y * 128, b = blockIdx.z;
    const int tid = threadIdx.x, lane = tid & 63, w = tid >> 6;
    const int wr = w >> 1, wc = w & 1;
    const int lr = lane & 15, lk8 = (lane >> 4) * 8;

    const int jmin = max(0, m0 - 64);
    const int jmax = min(DIM, m0 + 128 + 64);
    const int Kd0 = 2 * jmin;
    const int steps = (2 * (jmax - jmin)) >> 5;

    const unsigned short* gp = Gp + (size_t)(m0 + wr * 64 + lr) * 1024 + Kd0 + lk8;
    const unsigned short* xp = Xt + ((size_t)b * DIM + k0 + wc * 64 + lr) * 1024 + Kd0 + lk8;

    floatx4 acc[4][4];
#pragma unroll
    for (int ms = 0; ms < 4; ++ms)
#pragma unroll
        for (int ns = 0; ns < 4; ++ns) {
            acc[ms][ns][0] = 0.f; acc[ms][ns][1] = 0.f;
            acc[ms][ns][2] = 0.f; acc[ms][ns][3] = 0.f;
        }

#pragma unroll 4
    for (int s = 0; s < steps; ++s) {
        half8 a[4], bb[4];
#pragma unroll
        for (int ms = 0; ms < 4; ++ms)
            a[ms] = *reinterpret_cast<const half8*>(gp + (size_t)ms * 16 * 1024 + s * 32);
#pragma unroll
        for (int ns = 0; ns < 4; ++ns)
            bb[ns] = *reinterpret_cast<const half8*>(xp + (size_t)ns * 16 * 1024 + s * 32);
#pragma unroll
        for (int ms = 0; ms < 4; ++ms)
#pragma unroll
            for (int ns = 0; ns < 4; ++ns)
                acc[ms][ns] = __builtin_amdgcn_mfma_f32_16x16x32_f16(a[ms], bb[ns], acc[ms][ns], 0, 0, 0);
    }

    const int crow = (lane >> 4) * 4;
#pragma unroll
    for (int ms = 0; ms < 4; ++ms) {
#pragma unroll
        for (int ns = 0; ns < 4; ++ns) {
            const int kk = k0 + wc * 64 + ns * 16 + lr;
#pragma unroll
            for (int e = 0; e < 4; ++e) {
                const int m = m0 + wr * 64 + ms * 16 + crow + e;
                out[((size_t)b * DIM + m) * DIM + kk] = acc[ms][ns][e];
            }
        }
    }
}

// ---------------------------------------------------------------------------
// Fallback (r7-validated fp32 path) used only if ws_size is too small.
// ---------------------------------------------------------------------------
__global__ __launch_bounds__(256) void fold_gt(const float2* __restrict__ D,
                                               float2* __restrict__ Gt,
                                               const float* __restrict__ th1p,
                                               const float* __restrict__ th2p,
                                               const float* __restrict__ kapp) {
    const int idx = blockIdx.x * blockDim.x + threadIdx.x;
    const int m = idx & (DIM - 1), j = idx >> 9;
    const float theta = th1p[0] + th2p[0];
    const float kap = kapp[0];
    const float2 d = D[m * DIM + j];
    float sj, cj, sm, cm;
    sincosf(-theta * (float)j, &sj, &cj);
    sincosf(kap * (float)(m * m), &sm, &cm);
    const float r1 = d.x * cj - d.y * sj;
    const float i1 = d.x * sj + d.y * cj;
    const float r2 = r1 * cm - i1 * sm;
    const float i2 = r1 * sm + i1 * cm;
    Gt[idx] = make_float2(r2, -i2);
}

#define BM 128
#define BK 128
__global__ __launch_bounds__(256) void apply_real(const float2* __restrict__ Gt,
                                                  const float* __restrict__ xre,
                                                  const float* __restrict__ xim,
                                                  float* __restrict__ out) {
    __shared__ float2 As[16][BM];
    __shared__ float2 Bs[16][BK];
    const int k0 = blockIdx.x * BK, m0 = blockIdx.y * BM, bz = blockIdx.z;
    const int tid = threadIdx.x;
    const int tx = tid & 15, ty = tid >> 4;
    const int jmin = max(0, m0 - 64);
    const int jmax = min(DIM, m0 + BM + 64);
    const size_t xbase = (size_t)bz * DIM * DIM;

    float acc[8][8] = {{0.f}};
    for (int jt = jmin; jt < jmax; jt += 16) {
        for (int idx = tid; idx < 16 * BM; idx += 256) {
            const int l = idx >> 7, c = idx & (BM - 1);
            As[l][c] = Gt[(size_t)(jt + l) * DIM + m0 + c];
            const size_t xo = xbase + (size_t)(jt + l) * DIM + k0 + c;
            Bs[l][c] = make_float2(xre[xo], xim[xo]);
        }
        __syncthreads();
#pragma unroll
        for (int l = 0; l < 16; ++l) {
            float ar[8], ai[8], br[8], bi[8];
#pragma unroll
            for (int q = 0; q < 8; ++q) { float2 v = As[l][ty + 16 * q]; ar[q] = v.x; ai[q] = v.y; }
#pragma unroll
            for (int r = 0; r < 8; ++r) { float2 v = Bs[l][tx + 16 * r]; br[r] = v.x; bi[r] = v.y; }
#pragma unroll
            for (int q = 0; q < 8; ++q)
#pragma unroll
                for (int r = 0; r < 8; ++r)
                    acc[q][r] += ar[q] * br[r] + ai[q] * bi[r];
        }
        __syncthreads();
    }
#pragma unroll
    for (int q = 0; q < 8; ++q) {
        const int m = m0 + ty + 16 * q;
        const size_t off = (size_t)((size_t)bz * DIM + m) * DIM + k0 + tx;
#pragma unroll
        for (int r = 0; r < 8; ++r)
            out[off + 16 * r] = acc[q][r];
    }
}

// ---------------------------------------------------------------------------
extern "C" void kernel_launch(void* const* d_in, const int* in_sizes, int n_in,
                              void* d_out, int out_size, void* d_ws, size_t ws_size,
                              hipStream_t stream) {
    const float* xre = (const float*)d_in[0];
    const float* xim = (const float*)d_in[1];
    const float* th1 = (const float*)d_in[2];
    const float* th2 = (const float*)d_in[3];
    // d_in[4] = r : squeezing generator is exactly zero -> S = I, unused.
    const float* bx  = (const float*)d_in[5];
    const float* bp  = (const float*)d_in[6];
    const float* kap = (const float*)d_in[7];
    float* out = (float*)d_out;

    char* ws = (char*)d_ws;
    float2* bufA = (float2*)ws;                               // 2 MB
    float2* bufB = (float2*)(ws + 2u * 1024 * 1024);          // 2 MB
    unsigned short* Gp = (unsigned short*)(ws + 4u * 1024 * 1024);   // 1 MB
    unsigned short* Xt = (unsigned short*)(ws + 5u * 1024 * 1024);   // 33.6 MB
    const size_t need = 5u * 1024 * 1024 + (size_t)BATCH * DIM * 1024 * 2;

    // expm chain: E = expm(M/8); E^2; E^4; (E^8 + fold) — bands 16/24/40.
    hipLaunchKernelGGL(taylor_rows, dim3(128), dim3(256), 0, stream, bx, bp, bufA);
    hipLaunchKernelGGL(csq, dim3(8, 8), dim3(256), 0, stream, bufA, bufB, 16);
    hipLaunchKernelGGL(csq, dim3(8, 8), dim3(256), 0, stream, bufB, bufA, 24);

    if (ws_size >= need) {
        hipLaunchKernelGGL(csq_fold, dim3(8, 8), dim3(256), 0, stream,
                           bufA, Gp, th1, th2, kap, 40);
        hipLaunchKernelGGL(xt_build, dim3(8, 8, BATCH), dim3(256), 0, stream,
                           xre, xim, Xt);
        hipLaunchKernelGGL(apply_mfma, dim3(4, 4, BATCH), dim3(256), 0, stream,
                           Gp, Xt, out);
    } else {
        float2* bufC = (float2*)(ws + 4u * 1024 * 1024);      // fp32 Gt, 2 MB
        hipLaunchKernelGGL(csq, dim3(8, 8), dim3(256), 0, stream, bufA, bufB, 40);
        hipLaunchKernelGGL(fold_gt, dim3(DIM * DIM / 256), dim3(256), 0, stream,
                           bufB, bufC, th1, th2, kap);
        hipLaunchKernelGGL(apply_real, dim3(DIM / BK, DIM / BM, BATCH), dim3(256), 0, stream,
                           bufC, xre, xim, out);
    }
}